// Round 7
// baseline (292.357 us; speedup 1.0000x reference)
//
#include <hip/hip_runtime.h>
#include <hip/hip_bf16.h>

#define BATCH 16
#define NPTS 300000
#define NMS_PRE 2000
#define MAX_PER_IMG 1000
#define NBINS12 4096
#define KEY_SHIFT 20
#define CAND_CAP 8192
#define MASK_WORDS 32   // ceil(2000/64)
#define CNT_STRIDE 32   // pad per-batch counter to 128B

// ---------- ordered uint key for float (monotone increasing) ----------
__device__ __forceinline__ unsigned int fkey(float f) {
    unsigned int u = __float_as_uint(f);
    return (u & 0x80000000u) ? ~u : (u | 0x80000000u);
}

// ---------- K1: per-batch 4096-bin histogram (LDS-aggregated) ----------
__global__ __launch_bounds__(512) void k_hist(const float4* __restrict__ scores4,
                                              unsigned int* __restrict__ hist) {
    int b = blockIdx.y;
    __shared__ unsigned int H[NBINS12];
    for (int i = threadIdx.x; i < NBINS12; i += 512) H[i] = 0;
    __syncthreads();
    const float4* s = scores4 + (size_t)b * (NPTS / 4);
    int stride = gridDim.x * 512;
    for (int i = blockIdx.x * 512 + threadIdx.x; i < NPTS / 4; i += stride) {
        float4 v = s[i];
        atomicAdd(&H[fkey(v.x) >> KEY_SHIFT], 1u);
        atomicAdd(&H[fkey(v.y) >> KEY_SHIFT], 1u);
        atomicAdd(&H[fkey(v.z) >> KEY_SHIFT], 1u);
        atomicAdd(&H[fkey(v.w) >> KEY_SHIFT], 1u);
    }
    __syncthreads();
    unsigned int* h = hist + (size_t)b * NBINS12;
    for (int i = threadIdx.x; i < NBINS12; i += 512) {
        unsigned int c = H[i];
        if (c) atomicAdd(&h[i], c);
    }
}

// ---------- K2: find threshold bin ----------
__global__ __launch_bounds__(256) void k_findthr(const unsigned int* __restrict__ hist,
                                                 unsigned int* __restrict__ thrbin) {
    int b = blockIdx.x;
    const unsigned int* h = hist + (size_t)b * NBINS12;
    __shared__ unsigned int S[256];
    int t = threadIdx.x;
    unsigned int s = 0;
    for (int k = 0; k < 16; ++k) s += h[t * 16 + k];
    S[t] = s;
    __syncthreads();
    if (t == 0) {
        unsigned int acc = 0;
        int c = 255;
        for (; c > 0; --c) {
            if (acc + S[c] >= NMS_PRE) break;
            acc += S[c];
        }
        unsigned int T = (unsigned int)(c * 16);
        unsigned int a2 = acc;
        for (int bin = c * 16 + 15; bin >= c * 16; --bin) {
            a2 += h[bin];
            if (a2 >= NMS_PRE) { T = (unsigned int)bin; break; }
        }
        thrbin[b] = T;
    }
}

// ---------- K3: compact candidates with bin >= T (LDS-staged, 1 atomic/block) ----------
__global__ __launch_bounds__(256) void k_compact(const float4* __restrict__ scores4,
                                                 const unsigned int* __restrict__ thrbin,
                                                 unsigned int* __restrict__ cnt,
                                                 unsigned long long* __restrict__ cand) {
    int b = blockIdx.y;
    const float4* s = scores4 + (size_t)b * (NPTS / 4);
    unsigned int T = thrbin[b];
    unsigned long long* cb = cand + (size_t)b * CAND_CAP;
    __shared__ unsigned long long buf[1024];
    __shared__ unsigned int m, base;
    if (threadIdx.x == 0) m = 0;
    __syncthreads();
    int stride = gridDim.x * 256;
    for (int i = blockIdx.x * 256 + threadIdx.x; i < NPTS / 4; i += stride) {
        float4 v = s[i];
        float vv[4] = {v.x, v.y, v.z, v.w};
#pragma unroll
        for (int c = 0; c < 4; ++c) {
            unsigned int key = fkey(vv[c]);
            if ((key >> KEY_SHIFT) >= T) {
                unsigned int idx = (unsigned int)(i * 4 + c);
                unsigned long long pk = ((unsigned long long)key << 32) | (unsigned int)(~idx);
                unsigned int pos = atomicAdd(&m, 1u);
                if (pos < 1024) buf[pos] = pk;
                else {
                    unsigned int p2 = atomicAdd(&cnt[b * CNT_STRIDE], 1u);
                    if (p2 < CAND_CAP) cb[p2] = pk;
                }
            }
        }
    }
    __syncthreads();
    if (threadIdx.x == 0) {
        unsigned int mm = m < 1024u ? m : 1024u;
        base = atomicAdd(&cnt[b * CNT_STRIDE], mm);
        m = mm;
    }
    __syncthreads();
    unsigned int mm = m, bs = base;
    for (unsigned int i = threadIdx.x; i < mm; i += 256) {
        unsigned int p = bs + i;
        if (p < CAND_CAP) cb[p] = buf[i];
    }
}

// ---------- K4: bitonic sort desc by (key, ~idx); emit top-2000 indices ----------
__global__ __launch_bounds__(1024) void k_sort(const unsigned int* __restrict__ cnt,
                                               const unsigned long long* __restrict__ cand,
                                               unsigned int* __restrict__ selidx) {
    int b = blockIdx.x;
    __shared__ unsigned long long L[CAND_CAP];   // 64 KB
    unsigned int n = cnt[b * CNT_STRIDE];
    if (n > CAND_CAP) n = CAND_CAP;
    int P = 2048;
    while (P < (int)n) P <<= 1;
    const unsigned long long* cb = cand + (size_t)b * CAND_CAP;
    for (int i = threadIdx.x; i < P; i += 1024) L[i] = (i < (int)n) ? cb[i] : 0ull;
    __syncthreads();
    for (int k = 2; k <= P; k <<= 1) {
        for (int j = k >> 1; j > 0; j >>= 1) {
            for (int p = threadIdx.x; p < P / 2; p += 1024) {
                int i = ((p & ~(j - 1)) << 1) | (p & (j - 1));
                int l = i | j;
                bool up = ((i & k) == 0);
                unsigned long long a = L[i], c = L[l];
                if ((a < c) == up) { L[i] = c; L[l] = a; }
            }
            __syncthreads();
        }
    }
    for (int r = threadIdx.x; r < NMS_PRE; r += 1024) {
        unsigned int idx = ~(unsigned int)(L[r] & 0xFFFFFFFFull);
        if (idx >= NPTS) idx = 0;
        selidx[b * NMS_PRE + r] = idx;
    }
}

// ---------- K5: gather + delta2bbox decode + clip + max_coord ----------
__global__ __launch_bounds__(256) void k_decode(const float4* __restrict__ anchors4,
                                                const float4* __restrict__ deltas4,
                                                const float* __restrict__ scores,
                                                const int* __restrict__ levels,
                                                const unsigned int* __restrict__ selidx,
                                                float4* __restrict__ boxes4,
                                                float* __restrict__ ssel,
                                                int* __restrict__ lvlsel,
                                                float* __restrict__ mc) {
#pragma clang fp contract(off)
    int b = blockIdx.x;
    __shared__ float red[256];
    float m = 0.f;
    for (int r = threadIdx.x; r < NMS_PRE; r += 256) {
        unsigned int idx = selidx[b * NMS_PRE + r];
        size_t base = (size_t)b * NPTS + idx;
        float4 a = anchors4[base];
        float4 d = deltas4[base];
        const float MR = 4.135166556742356f;
        float d2 = fminf(fmaxf(d.z, -MR), MR);
        float d3 = fminf(fmaxf(d.w, -MR), MR);
        float px = (a.x + a.z) * 0.5f, py = (a.y + a.w) * 0.5f;
        float pw = a.z - a.x, ph = a.w - a.y;
        float gx = px + pw * d.x;
        float gy = py + ph * d.y;
        float gw = pw * expf(d2);
        float gh = ph * expf(d3);
        float x1 = gx - gw * 0.5f, y1 = gy - gh * 0.5f;
        float x2 = gx + gw * 0.5f, y2 = gy + gh * 0.5f;
        x1 = fminf(fmaxf(x1, 0.f), 1024.f);
        y1 = fminf(fmaxf(y1, 0.f), 1024.f);
        x2 = fminf(fmaxf(x2, 0.f), 1024.f);
        y2 = fminf(fmaxf(y2, 0.f), 1024.f);
        boxes4[(size_t)b * NMS_PRE + r] = make_float4(x1, y1, x2, y2);
        ssel[b * NMS_PRE + r] = scores[(size_t)b * NPTS + idx];
        lvlsel[b * NMS_PRE + r] = levels[(size_t)b * NPTS + idx];
        m = fmaxf(m, fmaxf(fmaxf(x1, y1), fmaxf(x2, y2)));
    }
    red[threadIdx.x] = m;
    __syncthreads();
    for (int s2 = 128; s2 > 0; s2 >>= 1) {
        if (threadIdx.x < s2) red[threadIdx.x] = fmaxf(red[threadIdx.x], red[threadIdx.x + s2]);
        __syncthreads();
    }
    if (threadIdx.x == 0) mc[b] = red[0];
}

// ---------- K6: pairwise IoU suppression bit-mask (64x64 tiles, zero lower-tri) ----------
__global__ __launch_bounds__(64) void k_mask(const float4* __restrict__ boxes4,
                                             const int* __restrict__ lvlsel,
                                             const float* __restrict__ mc,
                                             unsigned long long* __restrict__ mask) {
#pragma clang fp contract(off)
    int b = blockIdx.z, rowblk = blockIdx.y, colblk = blockIdx.x;
    int t = threadIdx.x;
    int i = rowblk * 64 + t;
    if (colblk < rowblk) {
        if (i < NMS_PRE)
            mask[((size_t)b * NMS_PRE + i) * MASK_WORDS + colblk] = 0ull;
        return;
    }
    __shared__ float bj[64][4];
    __shared__ float aj[64];
    float mcoff = mc[b] + 1.0f;
    int j0 = colblk * 64;
    int jj = j0 + t;
    if (jj < NMS_PRE) {
        float4 p = boxes4[(size_t)b * NMS_PRE + jj];
        float off = (float)lvlsel[b * NMS_PRE + jj] * mcoff;
        float x1 = p.x + off, y1 = p.y + off, x2 = p.z + off, y2 = p.w + off;
        bj[t][0] = x1; bj[t][1] = y1; bj[t][2] = x2; bj[t][3] = y2;
        aj[t] = (x2 - x1) * (y2 - y1);
    }
    __syncthreads();
    if (i >= NMS_PRE) return;
    float4 p = boxes4[(size_t)b * NMS_PRE + i];
    float off = (float)lvlsel[b * NMS_PRE + i] * mcoff;
    float ix1 = p.x + off, iy1 = p.y + off, ix2 = p.z + off, iy2 = p.w + off;
    float ai = (ix2 - ix1) * (iy2 - iy1);
    unsigned long long bits = 0;
    int jmax = min(64, NMS_PRE - j0);
    for (int q = 0; q < jmax; ++q) {
        int j = j0 + q;
        if (j <= i) continue;
        float ltx = fmaxf(ix1, bj[q][0]), lty = fmaxf(iy1, bj[q][1]);
        float rbx = fminf(ix2, bj[q][2]), rby = fminf(iy2, bj[q][3]);
        float w = fmaxf(rbx - ltx, 0.f);
        float h = fmaxf(rby - lty, 0.f);
        float inter = w * h;
        float uni = (ai + aj[q]) - inter;
        float iou = inter / fmaxf(uni, 1e-6f);
        if (iou > 0.7f) bits |= (1ull << q);
    }
    mask[((size_t)b * NMS_PRE + i) * MASK_WORDS + colblk] = bits;
}

// ---------- scan helpers (proven mm-chain, prefetch-pipelined) ----------
__device__ __forceinline__ void scan64(const unsigned long long* __restrict__ Sh, int w, int rw,
                                       unsigned long long& cur, unsigned long long& removedw) {
    unsigned long long rrA[8], dgA[8], rrB[8], dgB[8];
#define LOADG(rr, dg, q0)                                   \
    _Pragma("unroll")                                       \
    for (int k = 0; k < 8; ++k) {                           \
        rr[k] = Sh[((q0) + k) * MASK_WORDS + rw];           \
        dg[k] = Sh[((q0) + k) * MASK_WORDS + w];            \
    }
#define PROC(rr, dg, q0)                                    \
    _Pragma("unroll")                                       \
    for (int k = 0; k < 8; ++k) {                           \
        bool kept = !((cur >> ((q0) + k)) & 1ull);          \
        unsigned long long mm = kept ? ~0ull : 0ull;        \
        cur |= dg[k] & mm;                                  \
        removedw |= rr[k] & mm;                             \
    }
    LOADG(rrA, dgA, 0)
#pragma unroll
    for (int q0 = 0; q0 < 64; q0 += 16) {
        LOADG(rrB, dgB, q0 + 8)
        PROC(rrA, dgA, q0)
        if (q0 + 16 < 64) { LOADG(rrA, dgA, q0 + 16) }
        PROC(rrB, dgB, q0 + 8)
    }
#undef LOADG
#undef PROC
}

__device__ __forceinline__ void scan16(const unsigned long long* __restrict__ Sh, int w, int rw,
                                       unsigned long long& cur, unsigned long long& removedw) {
    unsigned long long rrA[8], dgA[8], rrB[8], dgB[8];
#define LOADG(rr, dg, q0)                                   \
    _Pragma("unroll")                                       \
    for (int k = 0; k < 8; ++k) {                           \
        rr[k] = Sh[((q0) + k) * MASK_WORDS + rw];           \
        dg[k] = Sh[((q0) + k) * MASK_WORDS + w];            \
    }
#define PROC(rr, dg, q0)                                    \
    _Pragma("unroll")                                       \
    for (int k = 0; k < 8; ++k) {                           \
        bool kept = !((cur >> ((q0) + k)) & 1ull);          \
        unsigned long long mm = kept ? ~0ull : 0ull;        \
        cur |= dg[k] & mm;                                  \
        removedw |= rr[k] & mm;                             \
    }
    LOADG(rrA, dgA, 0)
    LOADG(rrB, dgB, 8)
    PROC(rrA, dgA, 0)
    PROC(rrB, dgB, 8)
#undef LOADG
#undef PROC
}

// ---------- K7: NMS scan — full mask register-staged at kernel start ----------
// 1024 threads. Wave 0 scans; wave w (1..15) preloads slab w (128 rows, 32 KB)
// into 64 VGPRs at t=0 and dumps it to the LDS ping-pong slot during round w-1.
// No global loads inside the round loop -> HBM latency fully overlapped.
__global__ __launch_bounds__(1024) void k_nms_final(const unsigned long long* __restrict__ mask,
                                                    const float4* __restrict__ boxes4,
                                                    const float* __restrict__ ssel,
                                                    float* __restrict__ out) {
    int b = blockIdx.x;
    int t = threadIdx.x;
    int lane = t & 63;
    int wv = t >> 6;
    int rw = lane & 31;
    __shared__ __align__(16) unsigned long long stage[2][128 * MASK_WORDS];  // 2 x 32 KB
    __shared__ unsigned long long keepw[MASK_WORDS];
    __shared__ unsigned int sel[NMS_PRE];
    __shared__ unsigned int pcs[MASK_WORDS];
    __shared__ unsigned int count;

    const unsigned long long* mb = mask + (size_t)b * NMS_PRE * MASK_WORDS;
    const ulonglong2* mb2 = (const ulonglong2*)mb;

    ulonglong2 slab[32];   // producer-held slab (static-indexed -> registers)
    if (wv != 0) {
        // wave w: issue ALL loads for slab w now (rows w*128 .. w*128+127)
        int vrows = NMS_PRE - wv * 128; if (vrows > 128) vrows = 128;
        int nvec = vrows * (MASK_WORDS / 2);
        int sb = wv * 64 * MASK_WORDS;          // ulonglong2 index base
        ulonglong2 z; z.x = 0; z.y = 0;
#pragma unroll
        for (int k = 0; k < 32; ++k) {
            int idx = lane + 64 * k;
            slab[k] = (idx < nvec) ? mb2[sb + idx] : z;
        }
    } else {
        // wave 0: stage slab 0 straight into slot 0 (rows 0..127 all valid)
        ulonglong2* dst2 = (ulonglong2*)stage[0];
#pragma unroll
        for (int k = 0; k < 32; ++k) {
            int idx = lane + 64 * k;
            dst2[idx] = mb2[idx];
        }
    }
    __syncthreads();

    unsigned long long removedw = 0;  // lane r (<32) of wave 0 owns removed word r

    for (int r = 0; r < MASK_WORDS / 2; ++r) {
        if (wv == r + 1) {
            // dump my registers into slot (r+1)&1 for next round
            ulonglong2* dst2 = (ulonglong2*)stage[(r + 1) & 1];
#pragma unroll
            for (int k = 0; k < 32; ++k)
                dst2[lane + 64 * k] = slab[k];
        } else if (wv == 0) {
            const unsigned long long* S = stage[r & 1];
            {
                int w = 2 * r;
                unsigned long long cur = __shfl(removedw, w);
                scan64(S, w, rw, cur, removedw);
                if (lane == 0) keepw[w] = ~cur;
            }
            {
                int w = 2 * r + 1;
                const unsigned long long* Sh = S + 64 * MASK_WORDS;
                unsigned long long cur = __shfl(removedw, w);
                if (w < MASK_WORDS - 1) scan64(Sh, w, rw, cur, removedw);
                else                    scan16(Sh, w, rw, cur, removedw);
                if (lane == 0) keepw[w] = ~cur;
            }
        }
        __syncthreads();
    }

    // build sel list from keep words
    if (t == 0) keepw[MASK_WORDS - 1] &= (1ull << (NMS_PRE - 64 * (MASK_WORDS - 1))) - 1ull;
    __syncthreads();
    if (t < MASK_WORDS) pcs[t] = (unsigned int)__popcll(keepw[t]);
    __syncthreads();
    if (t < MASK_WORDS) {
        unsigned int pre = 0;
        for (int k = 0; k < t; ++k) pre += pcs[k];
        unsigned long long kw = keepw[t];
        unsigned int pos = pre;
        while (kw) {
            int q = __ffsll((long long)kw) - 1;
            sel[pos++] = (unsigned int)(t * 64 + q);
            kw &= kw - 1;
        }
        if (t == MASK_WORDS - 1) count = pos;
    }
    __syncthreads();

    unsigned int c = count;
    for (int r = t; r < MAX_PER_IMG; r += 1024) {
        float* o = out + ((size_t)b * MAX_PER_IMG + r) * 5;
        if (r < c) {
            unsigned int s = sel[r];
            float4 bx = boxes4[(size_t)b * NMS_PRE + s];
            o[0] = bx.x; o[1] = bx.y; o[2] = bx.z; o[3] = bx.w;
            o[4] = ssel[b * NMS_PRE + s];
        } else {
            o[0] = 0.f; o[1] = 0.f; o[2] = 0.f; o[3] = 0.f; o[4] = 0.f;
        }
    }
}

extern "C" void kernel_launch(void* const* d_in, const int* in_sizes, int n_in,
                              void* d_out, int out_size, void* d_ws, size_t ws_size,
                              hipStream_t stream) {
    const float* anchors = (const float*)d_in[0];
    const float* deltas  = (const float*)d_in[1];
    const float* scores  = (const float*)d_in[2];
    const int*   levels  = (const int*)d_in[3];
    float* out = (float*)d_out;
    char* ws = (char*)d_ws;

    size_t off = 0;
    auto alloc = [&](size_t bytes) {
        size_t p = off;
        off += (bytes + 255) & ~(size_t)255;
        return p;
    };
    size_t OFF_HIST = alloc((size_t)BATCH * NBINS12 * 4);
    size_t OFF_CNT  = alloc((size_t)BATCH * CNT_STRIDE * 4);
    size_t ZERO_END = off;
    size_t OFF_THR  = alloc((size_t)BATCH * 4);
    size_t OFF_CAND = alloc((size_t)BATCH * CAND_CAP * 8);
    size_t OFF_SEL  = alloc((size_t)BATCH * NMS_PRE * 4);
    size_t OFF_BOX  = alloc((size_t)BATCH * NMS_PRE * 4 * 4);
    size_t OFF_SS   = alloc((size_t)BATCH * NMS_PRE * 4);
    size_t OFF_LVL  = alloc((size_t)BATCH * NMS_PRE * 4);
    size_t OFF_MC   = alloc((size_t)BATCH * 4);
    size_t OFF_MASK = alloc((size_t)BATCH * NMS_PRE * MASK_WORDS * 8);
    if (off > ws_size) return;

    unsigned int* hist = (unsigned int*)(ws + OFF_HIST);
    unsigned int* cnt  = (unsigned int*)(ws + OFF_CNT);
    unsigned int* thr  = (unsigned int*)(ws + OFF_THR);
    unsigned long long* cand = (unsigned long long*)(ws + OFF_CAND);
    unsigned int* selidx = (unsigned int*)(ws + OFF_SEL);
    float4* boxes = (float4*)(ws + OFF_BOX);
    float* ssel  = (float*)(ws + OFF_SS);
    int*   lvls  = (int*)(ws + OFF_LVL);
    float* mc    = (float*)(ws + OFF_MC);
    unsigned long long* mask = (unsigned long long*)(ws + OFF_MASK);

    hipMemsetAsync(ws, 0, ZERO_END, stream);

    k_hist<<<dim3(16, BATCH), 512, 0, stream>>>((const float4*)scores, hist);
    k_findthr<<<BATCH, 256, 0, stream>>>(hist, thr);
    k_compact<<<dim3(32, BATCH), 256, 0, stream>>>((const float4*)scores, thr, cnt, cand);
    k_sort<<<BATCH, 1024, 0, stream>>>(cnt, cand, selidx);
    k_decode<<<BATCH, 256, 0, stream>>>((const float4*)anchors, (const float4*)deltas,
                                        scores, levels, selidx, boxes, ssel, lvls, mc);
    k_mask<<<dim3(32, 32, BATCH), 64, 0, stream>>>(boxes, lvls, mc, mask);
    k_nms_final<<<BATCH, 1024, 0, stream>>>(mask, boxes, ssel, out);
}

// Round 8
// 197.082 us; speedup vs baseline: 1.4834x; 1.4834x over previous
//
#include <hip/hip_runtime.h>
#include <hip/hip_bf16.h>

#define BATCH 16
#define NPTS 300000
#define NMS_PRE 2000
#define MAX_PER_IMG 1000
#define NBINS12 4096
#define KEY_SHIFT 20
#define CAND_CAP 8192
#define MASK_WORDS 32   // ceil(2000/64)
#define MASK_ROWS 2048  // padded row stride (16 slabs x 128 rows), OOB-safe slab reads
#define CNT_STRIDE 32   // pad per-batch counter to 128B

#define AS1(p) (const __attribute__((address_space(1))) void*)(p)
#define AS3(p) (__attribute__((address_space(3))) void*)(p)

// ---------- ordered uint key for float (monotone increasing) ----------
__device__ __forceinline__ unsigned int fkey(float f) {
    unsigned int u = __float_as_uint(f);
    return (u & 0x80000000u) ? ~u : (u | 0x80000000u);
}

// ---------- K1: per-batch 4096-bin histogram (LDS-aggregated) ----------
__global__ __launch_bounds__(512) void k_hist(const float4* __restrict__ scores4,
                                              unsigned int* __restrict__ hist) {
    int b = blockIdx.y;
    __shared__ unsigned int H[NBINS12];
    for (int i = threadIdx.x; i < NBINS12; i += 512) H[i] = 0;
    __syncthreads();
    const float4* s = scores4 + (size_t)b * (NPTS / 4);
    int stride = gridDim.x * 512;
    for (int i = blockIdx.x * 512 + threadIdx.x; i < NPTS / 4; i += stride) {
        float4 v = s[i];
        atomicAdd(&H[fkey(v.x) >> KEY_SHIFT], 1u);
        atomicAdd(&H[fkey(v.y) >> KEY_SHIFT], 1u);
        atomicAdd(&H[fkey(v.z) >> KEY_SHIFT], 1u);
        atomicAdd(&H[fkey(v.w) >> KEY_SHIFT], 1u);
    }
    __syncthreads();
    unsigned int* h = hist + (size_t)b * NBINS12;
    for (int i = threadIdx.x; i < NBINS12; i += 512) {
        unsigned int c = H[i];
        if (c) atomicAdd(&h[i], c);
    }
}

// ---------- K2: find threshold bin ----------
__global__ __launch_bounds__(256) void k_findthr(const unsigned int* __restrict__ hist,
                                                 unsigned int* __restrict__ thrbin) {
    int b = blockIdx.x;
    const unsigned int* h = hist + (size_t)b * NBINS12;
    __shared__ unsigned int S[256];
    int t = threadIdx.x;
    unsigned int s = 0;
    for (int k = 0; k < 16; ++k) s += h[t * 16 + k];
    S[t] = s;
    __syncthreads();
    if (t == 0) {
        unsigned int acc = 0;
        int c = 255;
        for (; c > 0; --c) {
            if (acc + S[c] >= NMS_PRE) break;
            acc += S[c];
        }
        unsigned int T = (unsigned int)(c * 16);
        unsigned int a2 = acc;
        for (int bin = c * 16 + 15; bin >= c * 16; --bin) {
            a2 += h[bin];
            if (a2 >= NMS_PRE) { T = (unsigned int)bin; break; }
        }
        thrbin[b] = T;
    }
}

// ---------- K3: compact candidates with bin >= T (LDS-staged, 1 atomic/block) ----------
__global__ __launch_bounds__(256) void k_compact(const float4* __restrict__ scores4,
                                                 const unsigned int* __restrict__ thrbin,
                                                 unsigned int* __restrict__ cnt,
                                                 unsigned long long* __restrict__ cand) {
    int b = blockIdx.y;
    const float4* s = scores4 + (size_t)b * (NPTS / 4);
    unsigned int T = thrbin[b];
    unsigned long long* cb = cand + (size_t)b * CAND_CAP;
    __shared__ unsigned long long buf[1024];
    __shared__ unsigned int m, base;
    if (threadIdx.x == 0) m = 0;
    __syncthreads();
    int stride = gridDim.x * 256;
    for (int i = blockIdx.x * 256 + threadIdx.x; i < NPTS / 4; i += stride) {
        float4 v = s[i];
        float vv[4] = {v.x, v.y, v.z, v.w};
#pragma unroll
        for (int c = 0; c < 4; ++c) {
            unsigned int key = fkey(vv[c]);
            if ((key >> KEY_SHIFT) >= T) {
                unsigned int idx = (unsigned int)(i * 4 + c);
                unsigned long long pk = ((unsigned long long)key << 32) | (unsigned int)(~idx);
                unsigned int pos = atomicAdd(&m, 1u);
                if (pos < 1024) buf[pos] = pk;
                else {
                    unsigned int p2 = atomicAdd(&cnt[b * CNT_STRIDE], 1u);
                    if (p2 < CAND_CAP) cb[p2] = pk;
                }
            }
        }
    }
    __syncthreads();
    if (threadIdx.x == 0) {
        unsigned int mm = m < 1024u ? m : 1024u;
        base = atomicAdd(&cnt[b * CNT_STRIDE], mm);
        m = mm;
    }
    __syncthreads();
    unsigned int mm = m, bs = base;
    for (unsigned int i = threadIdx.x; i < mm; i += 256) {
        unsigned int p = bs + i;
        if (p < CAND_CAP) cb[p] = buf[i];
    }
}

// ---------- K4: bitonic sort desc by (key, ~idx); emit top-2000 indices ----------
__global__ __launch_bounds__(1024) void k_sort(const unsigned int* __restrict__ cnt,
                                               const unsigned long long* __restrict__ cand,
                                               unsigned int* __restrict__ selidx) {
    int b = blockIdx.x;
    __shared__ unsigned long long L[CAND_CAP];   // 64 KB
    unsigned int n = cnt[b * CNT_STRIDE];
    if (n > CAND_CAP) n = CAND_CAP;
    int P = 2048;
    while (P < (int)n) P <<= 1;
    const unsigned long long* cb = cand + (size_t)b * CAND_CAP;
    for (int i = threadIdx.x; i < P; i += 1024) L[i] = (i < (int)n) ? cb[i] : 0ull;
    __syncthreads();
    for (int k = 2; k <= P; k <<= 1) {
        for (int j = k >> 1; j > 0; j >>= 1) {
            for (int p = threadIdx.x; p < P / 2; p += 1024) {
                int i = ((p & ~(j - 1)) << 1) | (p & (j - 1));
                int l = i | j;
                bool up = ((i & k) == 0);
                unsigned long long a = L[i], c = L[l];
                if ((a < c) == up) { L[i] = c; L[l] = a; }
            }
            __syncthreads();
        }
    }
    for (int r = threadIdx.x; r < NMS_PRE; r += 1024) {
        unsigned int idx = ~(unsigned int)(L[r] & 0xFFFFFFFFull);
        if (idx >= NPTS) idx = 0;
        selidx[b * NMS_PRE + r] = idx;
    }
}

// ---------- K5: gather + delta2bbox decode + clip + max_coord ----------
__global__ __launch_bounds__(256) void k_decode(const float4* __restrict__ anchors4,
                                                const float4* __restrict__ deltas4,
                                                const float* __restrict__ scores,
                                                const int* __restrict__ levels,
                                                const unsigned int* __restrict__ selidx,
                                                float4* __restrict__ boxes4,
                                                float* __restrict__ ssel,
                                                int* __restrict__ lvlsel,
                                                float* __restrict__ mc) {
#pragma clang fp contract(off)
    int b = blockIdx.x;
    __shared__ float red[256];
    float m = 0.f;
    for (int r = threadIdx.x; r < NMS_PRE; r += 256) {
        unsigned int idx = selidx[b * NMS_PRE + r];
        size_t base = (size_t)b * NPTS + idx;
        float4 a = anchors4[base];
        float4 d = deltas4[base];
        const float MR = 4.135166556742356f;
        float d2 = fminf(fmaxf(d.z, -MR), MR);
        float d3 = fminf(fmaxf(d.w, -MR), MR);
        float px = (a.x + a.z) * 0.5f, py = (a.y + a.w) * 0.5f;
        float pw = a.z - a.x, ph = a.w - a.y;
        float gx = px + pw * d.x;
        float gy = py + ph * d.y;
        float gw = pw * expf(d2);
        float gh = ph * expf(d3);
        float x1 = gx - gw * 0.5f, y1 = gy - gh * 0.5f;
        float x2 = gx + gw * 0.5f, y2 = gy + gh * 0.5f;
        x1 = fminf(fmaxf(x1, 0.f), 1024.f);
        y1 = fminf(fmaxf(y1, 0.f), 1024.f);
        x2 = fminf(fmaxf(x2, 0.f), 1024.f);
        y2 = fminf(fmaxf(y2, 0.f), 1024.f);
        boxes4[(size_t)b * NMS_PRE + r] = make_float4(x1, y1, x2, y2);
        ssel[b * NMS_PRE + r] = scores[(size_t)b * NPTS + idx];
        lvlsel[b * NMS_PRE + r] = levels[(size_t)b * NPTS + idx];
        m = fmaxf(m, fmaxf(fmaxf(x1, y1), fmaxf(x2, y2)));
    }
    red[threadIdx.x] = m;
    __syncthreads();
    for (int s2 = 128; s2 > 0; s2 >>= 1) {
        if (threadIdx.x < s2) red[threadIdx.x] = fmaxf(red[threadIdx.x], red[threadIdx.x + s2]);
        __syncthreads();
    }
    if (threadIdx.x == 0) mc[b] = red[0];
}

// ---------- K6: pairwise IoU suppression bit-mask (64x64 tiles, zero lower-tri) ----------
__global__ __launch_bounds__(64) void k_mask(const float4* __restrict__ boxes4,
                                             const int* __restrict__ lvlsel,
                                             const float* __restrict__ mc,
                                             unsigned long long* __restrict__ mask) {
#pragma clang fp contract(off)
    int b = blockIdx.z, rowblk = blockIdx.y, colblk = blockIdx.x;
    int t = threadIdx.x;
    int i = rowblk * 64 + t;
    if (colblk < rowblk) {
        if (i < NMS_PRE)
            mask[((size_t)b * MASK_ROWS + i) * MASK_WORDS + colblk] = 0ull;
        return;
    }
    __shared__ float bj[64][4];
    __shared__ float aj[64];
    float mcoff = mc[b] + 1.0f;
    int j0 = colblk * 64;
    int jj = j0 + t;
    if (jj < NMS_PRE) {
        float4 p = boxes4[(size_t)b * NMS_PRE + jj];
        float off = (float)lvlsel[b * NMS_PRE + jj] * mcoff;
        float x1 = p.x + off, y1 = p.y + off, x2 = p.z + off, y2 = p.w + off;
        bj[t][0] = x1; bj[t][1] = y1; bj[t][2] = x2; bj[t][3] = y2;
        aj[t] = (x2 - x1) * (y2 - y1);
    }
    __syncthreads();
    if (i >= NMS_PRE) return;
    float4 p = boxes4[(size_t)b * NMS_PRE + i];
    float off = (float)lvlsel[b * NMS_PRE + i] * mcoff;
    float ix1 = p.x + off, iy1 = p.y + off, ix2 = p.z + off, iy2 = p.w + off;
    float ai = (ix2 - ix1) * (iy2 - iy1);
    unsigned long long bits = 0;
    int jmax = min(64, NMS_PRE - j0);
    for (int q = 0; q < jmax; ++q) {
        int j = j0 + q;
        if (j <= i) continue;
        float ltx = fmaxf(ix1, bj[q][0]), lty = fmaxf(iy1, bj[q][1]);
        float rbx = fminf(ix2, bj[q][2]), rby = fminf(iy2, bj[q][3]);
        float w = fmaxf(rbx - ltx, 0.f);
        float h = fmaxf(rby - lty, 0.f);
        float inter = w * h;
        float uni = (ai + aj[q]) - inter;
        float iou = inter / fmaxf(uni, 1e-6f);
        if (iou > 0.7f) bits |= (1ull << q);
    }
    mask[((size_t)b * MASK_ROWS + i) * MASK_WORDS + colblk] = bits;
}

// ---------- scan helpers (proven mm-chain, prefetch-pipelined) ----------
__device__ __forceinline__ void scan64(const unsigned long long* __restrict__ Sh, int w, int rw,
                                       unsigned long long& cur, unsigned long long& removedw) {
    unsigned long long rrA[8], dgA[8], rrB[8], dgB[8];
#define LOADG(rr, dg, q0)                                   \
    _Pragma("unroll")                                       \
    for (int k = 0; k < 8; ++k) {                           \
        rr[k] = Sh[((q0) + k) * MASK_WORDS + rw];           \
        dg[k] = Sh[((q0) + k) * MASK_WORDS + w];            \
    }
#define PROC(rr, dg, q0)                                    \
    _Pragma("unroll")                                       \
    for (int k = 0; k < 8; ++k) {                           \
        bool kept = !((cur >> ((q0) + k)) & 1ull);          \
        unsigned long long mm = kept ? ~0ull : 0ull;        \
        cur |= dg[k] & mm;                                  \
        removedw |= rr[k] & mm;                             \
    }
    LOADG(rrA, dgA, 0)
#pragma unroll
    for (int q0 = 0; q0 < 64; q0 += 16) {
        LOADG(rrB, dgB, q0 + 8)
        PROC(rrA, dgA, q0)
        if (q0 + 16 < 64) { LOADG(rrA, dgA, q0 + 16) }
        PROC(rrB, dgB, q0 + 8)
    }
#undef LOADG
#undef PROC
}

__device__ __forceinline__ void scan16(const unsigned long long* __restrict__ Sh, int w, int rw,
                                       unsigned long long& cur, unsigned long long& removedw) {
    unsigned long long rrA[8], dgA[8], rrB[8], dgB[8];
#define LOADG(rr, dg, q0)                                   \
    _Pragma("unroll")                                       \
    for (int k = 0; k < 8; ++k) {                           \
        rr[k] = Sh[((q0) + k) * MASK_WORDS + rw];           \
        dg[k] = Sh[((q0) + k) * MASK_WORDS + w];            \
    }
#define PROC(rr, dg, q0)                                    \
    _Pragma("unroll")                                       \
    for (int k = 0; k < 8; ++k) {                           \
        bool kept = !((cur >> ((q0) + k)) & 1ull);          \
        unsigned long long mm = kept ? ~0ull : 0ull;        \
        cur |= dg[k] & mm;                                  \
        removedw |= rr[k] & mm;                             \
    }
    LOADG(rrA, dgA, 0)
    LOADG(rrB, dgB, 8)
    PROC(rrA, dgA, 0)
    PROC(rrB, dgB, 8)
#undef LOADG
#undef PROC
}

// ---------- K7: NMS scan — issue-early global_load_lds into 4-deep LDS ring ----------
// 320 threads (5 waves). Wave 0 scans slab r (128 rows) per round. Waves 1-4 own
// slabs (owner(s)=((s-1)&3)+1): owner of slab r+3 ISSUES its 32 global_load_lds
// in round r (slot freed after round r-1); owner of slab r+1 drains vmcnt(0)
// before the round-r barrier. Raw s_barrier per round (no implicit vmcnt drain).
__global__ __launch_bounds__(320) void k_nms_final(const unsigned long long* __restrict__ mask,
                                                   const float4* __restrict__ boxes4,
                                                   const float* __restrict__ ssel,
                                                   float* __restrict__ out) {
    int b = blockIdx.x;
    int t = threadIdx.x;
    int lane = t & 63;
    int wv = t >> 6;
    int rw = lane & 31;
    __shared__ __align__(16) unsigned long long stage[4][128 * MASK_WORDS];  // 4 x 32 KB
    __shared__ unsigned long long keepw[MASK_WORDS];
    __shared__ unsigned int sel[NMS_PRE];
    __shared__ unsigned int pcs[MASK_WORDS];
    __shared__ unsigned int count;

    const unsigned long long* mb = mask + (size_t)b * MASK_ROWS * MASK_WORDS;
    const ulonglong2* mb2 = (const ulonglong2*)mb;

    // cooperative synchronous stage of slab 0 into slot 0
    {
        ulonglong2* dst2 = (ulonglong2*)stage[0];
        for (int idx = t; idx < 64 * MASK_WORDS; idx += 320)
            dst2[idx] = mb2[idx];
    }
    // waves 1,2: issue slabs 1,2 (drained by the __syncthreads below — safe head start)
    if (wv == 1 || wv == 2) {
        const ulonglong2* src = mb2 + wv * (64 * MASK_WORDS);
        ulonglong2* dst = (ulonglong2*)stage[wv & 3];
#pragma unroll
        for (int k = 0; k < 32; ++k)
            __builtin_amdgcn_global_load_lds(AS1(src + k * 64 + lane), AS3(dst + k * 64), 16, 0, 0);
    }
    __syncthreads();

    unsigned long long removedw = 0;  // lane r (<32) of wave 0 owns removed word r

    for (int r = 0; r < MASK_WORDS / 2; ++r) {
        if (wv == 0) {
            const unsigned long long* S = stage[r & 3];
            {
                int w = 2 * r;
                unsigned long long cur = __shfl(removedw, w);
                scan64(S, w, rw, cur, removedw);
                if (lane == 0) keepw[w] = ~cur;
            }
            {
                int w = 2 * r + 1;
                const unsigned long long* Sh = S + 64 * MASK_WORDS;
                unsigned long long cur = __shfl(removedw, w);
                if (w < MASK_WORDS - 1) scan64(Sh, w, rw, cur, removedw);
                else                    scan16(Sh, w, rw, cur, removedw);
                if (lane == 0) keepw[w] = ~cur;
            }
        } else {
            int si = r + 3;                       // slab to issue this round
            if (si < 16 && (((si - 1) & 3) + 1) == wv) {
                const ulonglong2* src = mb2 + si * (64 * MASK_WORDS);
                ulonglong2* dst = (ulonglong2*)stage[si & 3];
#pragma unroll
                for (int k = 0; k < 32; ++k)
                    __builtin_amdgcn_global_load_lds(AS1(src + k * 64 + lane), AS3(dst + k * 64), 16, 0, 0);
            }
            int sw = r + 1;                       // slab needed next round
            if (sw < 16 && (((sw - 1) & 3) + 1) == wv)
                asm volatile("s_waitcnt vmcnt(0)" ::: "memory");
        }
        asm volatile("" ::: "memory");
        __builtin_amdgcn_s_barrier();
        asm volatile("" ::: "memory");
    }
    __syncthreads();

    // build sel list from keep words
    if (t == 0) keepw[MASK_WORDS - 1] &= (1ull << (NMS_PRE - 64 * (MASK_WORDS - 1))) - 1ull;
    __syncthreads();
    if (t < MASK_WORDS) pcs[t] = (unsigned int)__popcll(keepw[t]);
    __syncthreads();
    if (t < MASK_WORDS) {
        unsigned int pre = 0;
        for (int k = 0; k < t; ++k) pre += pcs[k];
        unsigned long long kw = keepw[t];
        unsigned int pos = pre;
        while (kw) {
            int q = __ffsll((long long)kw) - 1;
            sel[pos++] = (unsigned int)(t * 64 + q);
            kw &= kw - 1;
        }
        if (t == MASK_WORDS - 1) count = pos;
    }
    __syncthreads();

    unsigned int c = count;
    for (int r = t; r < MAX_PER_IMG; r += 320) {
        float* o = out + ((size_t)b * MAX_PER_IMG + r) * 5;
        if (r < c) {
            unsigned int s = sel[r];
            float4 bx = boxes4[(size_t)b * NMS_PRE + s];
            o[0] = bx.x; o[1] = bx.y; o[2] = bx.z; o[3] = bx.w;
            o[4] = ssel[b * NMS_PRE + s];
        } else {
            o[0] = 0.f; o[1] = 0.f; o[2] = 0.f; o[3] = 0.f; o[4] = 0.f;
        }
    }
}

extern "C" void kernel_launch(void* const* d_in, const int* in_sizes, int n_in,
                              void* d_out, int out_size, void* d_ws, size_t ws_size,
                              hipStream_t stream) {
    const float* anchors = (const float*)d_in[0];
    const float* deltas  = (const float*)d_in[1];
    const float* scores  = (const float*)d_in[2];
    const int*   levels  = (const int*)d_in[3];
    float* out = (float*)d_out;
    char* ws = (char*)d_ws;

    size_t off = 0;
    auto alloc = [&](size_t bytes) {
        size_t p = off;
        off += (bytes + 255) & ~(size_t)255;
        return p;
    };
    size_t OFF_HIST = alloc((size_t)BATCH * NBINS12 * 4);
    size_t OFF_CNT  = alloc((size_t)BATCH * CNT_STRIDE * 4);
    size_t ZERO_END = off;
    size_t OFF_THR  = alloc((size_t)BATCH * 4);
    size_t OFF_CAND = alloc((size_t)BATCH * CAND_CAP * 8);
    size_t OFF_SEL  = alloc((size_t)BATCH * NMS_PRE * 4);
    size_t OFF_BOX  = alloc((size_t)BATCH * NMS_PRE * 4 * 4);
    size_t OFF_SS   = alloc((size_t)BATCH * NMS_PRE * 4);
    size_t OFF_LVL  = alloc((size_t)BATCH * NMS_PRE * 4);
    size_t OFF_MC   = alloc((size_t)BATCH * 4);
    size_t OFF_MASK = alloc((size_t)BATCH * MASK_ROWS * MASK_WORDS * 8);  // 8.4 MB
    if (off > ws_size) return;

    unsigned int* hist = (unsigned int*)(ws + OFF_HIST);
    unsigned int* cnt  = (unsigned int*)(ws + OFF_CNT);
    unsigned int* thr  = (unsigned int*)(ws + OFF_THR);
    unsigned long long* cand = (unsigned long long*)(ws + OFF_CAND);
    unsigned int* selidx = (unsigned int*)(ws + OFF_SEL);
    float4* boxes = (float4*)(ws + OFF_BOX);
    float* ssel  = (float*)(ws + OFF_SS);
    int*   lvls  = (int*)(ws + OFF_LVL);
    float* mc    = (float*)(ws + OFF_MC);
    unsigned long long* mask = (unsigned long long*)(ws + OFF_MASK);

    hipMemsetAsync(ws, 0, ZERO_END, stream);

    k_hist<<<dim3(16, BATCH), 512, 0, stream>>>((const float4*)scores, hist);
    k_findthr<<<BATCH, 256, 0, stream>>>(hist, thr);
    k_compact<<<dim3(32, BATCH), 256, 0, stream>>>((const float4*)scores, thr, cnt, cand);
    k_sort<<<BATCH, 1024, 0, stream>>>(cnt, cand, selidx);
    k_decode<<<BATCH, 256, 0, stream>>>((const float4*)anchors, (const float4*)deltas,
                                        scores, levels, selidx, boxes, ssel, lvls, mc);
    k_mask<<<dim3(32, 32, BATCH), 64, 0, stream>>>(boxes, lvls, mc, mask);
    k_nms_final<<<BATCH, 320, 0, stream>>>(mask, boxes, ssel, out);
}